// Round 1
// baseline (136.862 us; speedup 1.0000x reference)
//
#include <hip/hip_runtime.h>
#include <hip/hip_bf16.h>
#include <hip/hip_cooperative_groups.h>
#include <math.h>

namespace cg = cooperative_groups;

// B=1024, F=4096, D=32: s = data@embed, out = sigmoid(gb + data@bias + ||s||^2)
//
// R6: single cooperative kernel. Evidence: top-5 rocprof dispatches are all 43us
// harness fills at 6.3 TB/s; our honest traffic is ~22 MB (~3.5us) yet dur=71.5us,
// so the time is structural (2 serialized launches, 2048 micro-blocks, 4 MB ws
// round-trip), not bandwidth. New shape: 256 blocks (1/CU, co-resident => grid.sync
// legal) x 512 threads; block = 16 rows x K=1024 quadrant (MT=16, KS=4). Whole tile
// staged in one LDS shot (117 KB), 8 MFMAs/wave, block reduce, 512 KB partials,
// grid.sync, fused finalize. One launch, max loads in flight, no inter-kernel drain.

#define F_DIM 4096
#define D_DIM 32
#define B_DIM 1024
#define MT 16               // rows per block
#define KS 4                // K splits
#define KC 1024             // k per block
#define LDA 1032            // shorts per LDS row: 2064B stride = 16B-aligned, bank stride 4 (2-way = free)
#define NTHREADS 512

typedef __attribute__((ext_vector_type(8))) short short8;   // MFMA A/B frag (8 bf16)
typedef __attribute__((ext_vector_type(4))) float f32x4;    // MFMA C/D frag

__device__ inline unsigned int pkbf(float a, float b) {     // 2x fp32 -> packed bf16 (RNE)
    __hip_bfloat162 h = __float22bfloat162_rn(make_float2(a, b));
    union { __hip_bfloat162 h2; unsigned int u; } c; c.h2 = h;
    return c.u;   // low 16 = a, high 16 = b
}

__global__ __launch_bounds__(NTHREADS, 2) void fm_fused(
    const float* __restrict__ data, const float* __restrict__ embed,
    const float* __restrict__ bias, const float* __restrict__ gbias,
    float* __restrict__ ws_s, float* __restrict__ ws_b,
    float* __restrict__ out)
{
    __shared__ short lA [MT][LDA];            // 16x1024 bf16 A tile     (32.25 KB)
    __shared__ short lBT[D_DIM][LDA];         // 32x1024 bf16 B^T tile   (64.5 KB)
    __shared__ float redCT[8][2][16][20];     // C frags [w][nt][col][row] (20 KB)

    const int t  = threadIdx.x;
    const int w  = t >> 6;                    // wave 0..7
    const int l  = t & 63;
    const int mt = blockIdx.x >> 2;           // M-tile 0..63
    const int ks = blockIdx.x & 3;            // K-split 0..3
    const int m0 = mt * MT;
    const int kb = ks * KC;

    // ---- stage A (+ exact fp32 bias-term partials): 32 threads per row, 8x float4 each ----
    {
        const int r  = t >> 5;                // 0..15
        const int c4 = (t & 31) * 4;          // col base within each 128-float stripe
        const float* dro = data + (size_t)(m0 + r) * F_DIM + kb;
        const float* bro = bias + kb;
        float bt = 0.f;
        #pragma unroll
        for (int jj = 0; jj < 8; ++jj) {
            const int col = c4 + jj * 128;
            const float4 x  = *(const float4*)(dro + col);   // 32 lanes x 16B = 512B coalesced
            const float4 bv = *(const float4*)(bro + col);   // broadcast across rows, L2-hot
            bt = fmaf(x.x, bv.x, bt);
            bt = fmaf(x.y, bv.y, bt);
            bt = fmaf(x.z, bv.z, bt);
            bt = fmaf(x.w, bv.w, bt);
            uint2 pk;
            pk.x = pkbf(x.x, x.y);
            pk.y = pkbf(x.z, x.w);
            *(uint2*)(&lA[r][col]) = pk;      // ds_write_b64, 8B-aligned
        }
        // reduce bias partial across the 32 threads of this row (one half-wave)
        bt += __shfl_xor(bt, 1);  bt += __shfl_xor(bt, 2);
        bt += __shfl_xor(bt, 4);  bt += __shfl_xor(bt, 8);
        bt += __shfl_xor(bt, 16);
        if ((t & 31) == 0) ws_b[(size_t)(m0 + r) * KS + ks] = bt;
    }

    // ---- stage B^T: thread owns d-pair (t&15)*2, walks 4 k-octets of 8 ----
    {
        const int d2 = (t & 15) * 2;
        const int kq = t >> 4;                // 0..31
        #pragma unroll
        for (int ko = 0; ko < 4; ++ko) {
            const int k8 = kq * 8 + ko * 256; // 0..1016 step 8
            const float* ep = embed + (size_t)(kb + k8) * D_DIM + d2;
            float2 e[8];
            #pragma unroll
            for (int j = 0; j < 8; ++j) e[j] = *(const float2*)(ep + (size_t)j * D_DIM);
            uint4 ux, uy;
            ux.x = pkbf(e[0].x, e[1].x); ux.y = pkbf(e[2].x, e[3].x);
            ux.z = pkbf(e[4].x, e[5].x); ux.w = pkbf(e[6].x, e[7].x);
            uy.x = pkbf(e[0].y, e[1].y); uy.y = pkbf(e[2].y, e[3].y);
            uy.z = pkbf(e[4].y, e[5].y); uy.w = pkbf(e[6].y, e[7].y);
            *(uint4*)(&lBT[d2    ][k8]) = ux; // ds_write_b128, 16B-aligned
            *(uint4*)(&lBT[d2 + 1][k8]) = uy;
        }
    }
    __syncthreads();

    // ---- MFMA: wave w owns k-slab [w*128, w*128+128): 4x (16x16x32) per n-tile, K-accumulated ----
    const int quad = l >> 4;
    const int mrow = l & 15;
    f32x4 acc0 = {0.f, 0.f, 0.f, 0.f};
    f32x4 acc1 = {0.f, 0.f, 0.f, 0.f};
    #pragma unroll
    for (int s = 0; s < 4; ++s) {
        const int kk = w * 128 + s * 32 + quad * 8;
        const short8 a  = *(const short8*)(&lA [mrow     ][kk]);
        const short8 b0 = *(const short8*)(&lBT[mrow     ][kk]);   // d = 0..15
        const short8 b1 = *(const short8*)(&lBT[16 + mrow][kk]);   // d = 16..31
        acc0 = __builtin_amdgcn_mfma_f32_16x16x32_bf16(a, b0, acc0, 0, 0, 0);
        acc1 = __builtin_amdgcn_mfma_f32_16x16x32_bf16(a, b1, acc1, 0, 0, 0);
    }

    // ---- K-reduce 8 waves' C frags. C layout: col=lane&15, row=quad*4+reg (verified R4).
    *(f32x4*)(&redCT[w][0][mrow][quad * 4]) = acc0;
    *(f32x4*)(&redCT[w][1][mrow][quad * 4]) = acc1;
    __syncthreads();

    {
        const int nt = t >> 8;                // 512 outputs: (nt, r, c), 1 per thread
        const int rr = (t >> 4) & 15;
        const int cc = t & 15;
        float v = 0.f;
        #pragma unroll
        for (int ww = 0; ww < 8; ++ww) v += redCT[ww][nt][cc][rr];
        ws_s[((size_t)(m0 + rr) * KS + ks) * D_DIM + nt * 16 + cc] = v;
    }

    // ---- grid-wide sync (all 256 blocks co-resident: 1/CU), then fused finalize ----
    __threadfence();
    cg::this_grid().sync();

    // waves 0..3: one row each. Row partials = [KS=4][D=32] = 128 floats contiguous.
    if (w < 4) {
        const int row = blockIdx.x * 4 + w;
        float2 v = ((const float2*)(ws_s + (size_t)row * KS * D_DIM))[l];  // lane l: ks=l>>4, d=(2l)&31
        v.x += __shfl_xor(v.x, 16); v.y += __shfl_xor(v.y, 16);            // sum over ks
        v.x += __shfl_xor(v.x, 32); v.y += __shfl_xor(v.y, 32);
        float c = (l < 16) ? fmaf(v.x, v.x, v.y * v.y) : 0.f;              // lanes 0..15 = d-pairs
        if (l < 4) c += ws_b[(size_t)row * KS + l];                        // 4 bias partials
        #pragma unroll
        for (int m = 1; m <= 32; m <<= 1) c += __shfl_xor(c, m);
        if (l == 0) {
            const float x = gbias[0] + c;
            out[row] = 1.0f / (1.0f + __expf(-x));
        }
    }
}

extern "C" void kernel_launch(void* const* d_in, const int* in_sizes, int n_in,
                              void* d_out, int out_size, void* d_ws, size_t ws_size,
                              hipStream_t stream) {
    const float* data  = (const float*)d_in[0];
    const float* embed = (const float*)d_in[1];
    const float* bias  = (const float*)d_in[2];
    const float* gb    = (const float*)d_in[3];
    float* out  = (float*)d_out;

    float* ws_s = (float*)d_ws;                                  // 1024*4*32 f = 512 KB
    float* ws_b = (float*)d_ws + (size_t)B_DIM * KS * D_DIM;     // 1024*4 f

    void* args[7];
    args[0] = (void*)&data;  args[1] = (void*)&embed; args[2] = (void*)&bias;
    args[3] = (void*)&gb;    args[4] = (void*)&ws_s;  args[5] = (void*)&ws_b;
    args[6] = (void*)&out;

    hipLaunchCooperativeKernel((void*)fm_fused,
                               dim3(B_DIM / MT * KS),   // 256 blocks = 1 per CU
                               dim3(NTHREADS), args, 0, stream);
}

// Round 2
// 71.078 us; speedup vs baseline: 1.9255x; 1.9255x over previous
//
#include <hip/hip_runtime.h>
#include <hip/hip_bf16.h>
#include <math.h>

// B=1024, F=4096, D=32: s = data@embed, out = sigmoid(gb + data@bias + ||s||^2)
//
// R7: revert cooperative fusion (R6 post-mortem: coop launch is not graph-capturable,
// +38us host overhead in timed region; 1 block/CU + grid.sync serialized every CU's
// latency chain -> 55us kernel). Back to 2 graph-captured launches; kernel 1 made lean:
//  - A-frags loaded DIRECTLY from global (no A-LDS write/sync/read round trip); wave's
//    4 quads tile each row's 128B per k-step contiguously -> fully coalesced, read once.
//  - wave owns 16 ROWS x full KC (MT=64) instead of a k-slab -> no cross-wave C
//    reduction, no redCT LDS, one __syncthreads total; C-frags stored straight to
//    ws_s[row][ks][d] (64B segments per quad).
//  - bias folded in as a 33rd bf16 B-column (MFMA n-tile 2, col 0) -> separate fp32
//    bias pass + 10-shuffle reduce deleted. (Outputs saturate; bf16 slop is forgiven.)
//  - only LDS: 13KB B^T tile -> 512 small blocks, deep co-residency, short chains.
// fm_final is R0's verified kernel, byte-for-byte (same KS=32, same ws layout).

#define F_DIM 4096
#define D_DIM 32
#define B_DIM 1024
#define MT 64               // rows per block = 16 per wave x 4 waves
#define KS 32               // K splits
#define KC 128              // k per block
#define LDB 136             // shorts per LDS row: 272B stride (16B-aligned, even bank spread)
#define NW 4

typedef __attribute__((ext_vector_type(8))) short short8;   // MFMA A/B frag (8 bf16)
typedef __attribute__((ext_vector_type(4))) float f32x4;    // MFMA C/D frag

__device__ inline unsigned int pkbf(float a, float b) {     // 2x fp32 -> packed bf16 (RNE)
    __hip_bfloat162 h = __float22bfloat162_rn(make_float2(a, b));
    union { __hip_bfloat162 h2; unsigned int u; } c; c.h2 = h;
    return c.u;   // low 16 = a, high 16 = b
}

__device__ inline short8 as_short8(uint4 u) {
    union { uint4 v; short8 s; } c; c.v = u; return c.s;
}

__global__ __launch_bounds__(256, 4) void fm_gemm(const float* __restrict__ data,
                                                  const float* __restrict__ embed,
                                                  const float* __restrict__ bias,
                                                  float* __restrict__ ws_s,
                                                  float* __restrict__ ws_b)
{
    // rows 0..31: embed^T (bf16), row 32: bias (bf16), rows 33..47: never written;
    // garbage there only feeds C cols 1..15 of the bias n-tile, which are discarded.
    __shared__ short lBT[48][LDB];                // 12.75 KB

    const int t  = threadIdx.x;
    const int w  = t >> 6;                        // wave 0..3 -> rows [w*16, w*16+16)
    const int l  = t & 63;
    const int mt = blockIdx.x >> 5;               // M-tile 0..15
    const int ks = blockIdx.x & 31;               // K-split 0..31
    const int m0 = mt * MT;
    const int kb = ks * KC;

    // ---- stage B^T: thread owns d-pair (t&15)*2 and k-octet (t>>4)*8 (exactly 256 slots)
    {
        const int d2 = (t & 15) * 2;
        const int k8 = (t >> 4) * 8;
        const float* ep = embed + (size_t)(kb + k8) * D_DIM + d2;
        float2 e[8];
        #pragma unroll
        for (int j = 0; j < 8; ++j) e[j] = *(const float2*)(ep + (size_t)j * D_DIM);
        uint4 ux, uy;
        ux.x = pkbf(e[0].x, e[1].x); ux.y = pkbf(e[2].x, e[3].x);
        ux.z = pkbf(e[4].x, e[5].x); ux.w = pkbf(e[6].x, e[7].x);
        uy.x = pkbf(e[0].y, e[1].y); uy.y = pkbf(e[2].y, e[3].y);
        uy.z = pkbf(e[4].y, e[5].y); uy.w = pkbf(e[6].y, e[7].y);
        *(uint4*)(&lBT[d2    ][k8]) = ux;         // ds_write_b128, 16B-aligned
        *(uint4*)(&lBT[d2 + 1][k8]) = uy;
    }
    // ---- stage bias row (bf16) as B-column 32: threads 0..15, 8 k each
    if (t < 16) {
        const float4 b0 = *(const float4*)(bias + kb + t * 8);
        const float4 b1 = *(const float4*)(bias + kb + t * 8 + 4);
        uint4 u;
        u.x = pkbf(b0.x, b0.y); u.y = pkbf(b0.z, b0.w);
        u.z = pkbf(b1.x, b1.y); u.w = pkbf(b1.z, b1.w);
        *(uint4*)(&lBT[32][t * 8]) = u;
    }
    __syncthreads();

    // ---- MFMA: A-frags direct from global. A layout: lane holds row l&15, k quad*8+0..7.
    const int quad = l >> 4;
    const int c    = l & 15;
    const float* arow = data + (size_t)(m0 + w * 16 + c) * F_DIM + kb;

    f32x4 acc0 = {0.f, 0.f, 0.f, 0.f};           // d = 0..15
    f32x4 acc1 = {0.f, 0.f, 0.f, 0.f};           // d = 16..31
    f32x4 acc2 = {0.f, 0.f, 0.f, 0.f};           // col 0 = bias term
    #pragma unroll
    for (int s = 0; s < 4; ++s) {
        const int kk = s * 32 + quad * 8;
        const float4 x0 = *(const float4*)(arow + kk);
        const float4 x1 = *(const float4*)(arow + kk + 4);
        uint4 ua;
        ua.x = pkbf(x0.x, x0.y); ua.y = pkbf(x0.z, x0.w);
        ua.z = pkbf(x1.x, x1.y); ua.w = pkbf(x1.z, x1.w);
        const short8 a  = as_short8(ua);
        const short8 b0 = *(const short8*)(&lBT[c     ][kk]);
        const short8 b1 = *(const short8*)(&lBT[16 + c][kk]);
        const short8 b2 = *(const short8*)(&lBT[32 + c][kk]);
        acc0 = __builtin_amdgcn_mfma_f32_16x16x32_bf16(a, b0, acc0, 0, 0, 0);
        acc1 = __builtin_amdgcn_mfma_f32_16x16x32_bf16(a, b1, acc1, 0, 0, 0);
        acc2 = __builtin_amdgcn_mfma_f32_16x16x32_bf16(a, b2, acc2, 0, 0, 0);
    }

    // ---- epilogue: C layout row=quad*4+j, col=c (verified R4). Store to [row][ks][d].
    const int rbase = m0 + w * 16 + quad * 4;
    #pragma unroll
    for (int j = 0; j < 4; ++j) {
        float* p = ws_s + ((size_t)(rbase + j) * KS + ks) * D_DIM;
        p[c]      = acc0[j];                      // 16 lanes -> one 64B segment
        p[16 + c] = acc1[j];
    }
    if (c == 0) {
        #pragma unroll
        for (int j = 0; j < 4; ++j)
            ws_b[(size_t)(rbase + j) * KS + ks] = acc2[j];
    }
}

// One wave per output row: row's 32x32 K-partials are 4KB contiguous = one float4/lane.
// (R0-verified, unchanged.)
__global__ __launch_bounds__(256, 4) void fm_final(const float* __restrict__ ws_s,
                                                   const float* __restrict__ ws_b,
                                                   const float* __restrict__ gbias,
                                                   float* __restrict__ out)
{
    const int t = threadIdx.x;
    const int w = t >> 6;
    const int l = t & 63;
    const int row = blockIdx.x * 4 + w;

    float4 v = ((const float4*)(ws_s + (size_t)row * KS * D_DIM))[l];  // lane l: k=l>>3, d=(4l)&31
    #pragma unroll
    for (int m = 8; m <= 32; m <<= 1) {       // reduce over k (lanes sharing l&7)
        v.x += __shfl_xor(v.x, m); v.y += __shfl_xor(v.y, m);
        v.z += __shfl_xor(v.z, m); v.w += __shfl_xor(v.w, m);
    }
    float c = 0.f;
    if (l < 8)  c = v.x * v.x + v.y * v.y + v.z * v.z + v.w * v.w;  // lanes 0..7 = d-groups
    if (l < 32) c += ws_b[(size_t)row * KS + l];                    // 32 bias partials
    #pragma unroll
    for (int m = 1; m <= 32; m <<= 1) c += __shfl_xor(c, m);
    if (l == 0) {
        const float x = gbias[0] + c;
        out[row] = 1.0f / (1.0f + __expf(-x));
    }
}

extern "C" void kernel_launch(void* const* d_in, const int* in_sizes, int n_in,
                              void* d_out, int out_size, void* d_ws, size_t ws_size,
                              hipStream_t stream) {
    const float* data  = (const float*)d_in[0];
    const float* embed = (const float*)d_in[1];
    const float* bias  = (const float*)d_in[2];
    const float* gb    = (const float*)d_in[3];
    float* out  = (float*)d_out;

    float* ws_s = (float*)d_ws;                                  // 1024*32*32 f = 4 MB
    float* ws_b = (float*)d_ws + (size_t)B_DIM * KS * D_DIM;     // 1024*32 f

    dim3 gridA(16 * KS);     // 512 blocks = 16 M-tiles x 32 K-splits
    dim3 blockA(256);
    fm_gemm<<<gridA, blockA, 0, stream>>>(data, embed, bias, ws_s, ws_b);

    dim3 gridB(B_DIM / 4);   // 256 blocks, one wave per row
    dim3 blockB(256);
    fm_final<<<gridB, blockB, 0, stream>>>(ws_s, ws_b, gb, out);
}